// Round 15
// baseline (133.731 us; speedup 1.0000x reference)
//
#include <hip/hip_runtime.h>

#define N_NODES 50000
#define D 128
#define R 8
#define E_EDGES 600000
#define NR (N_NODES * R)                 // 400000 (rel,dst) keys: key = r*N + dst
#define SCAN_BLOCKS ((NR + 1023) / 1024) // 391 (fallback path only)
#define SLOTS_K 16

typedef unsigned short ushort_t;
typedef unsigned int uint_t;
typedef __attribute__((ext_vector_type(8))) short short8;
typedef __attribute__((ext_vector_type(8))) ushort_t ushort8;
typedef __attribute__((ext_vector_type(4))) float f32x4;
typedef __attribute__((ext_vector_type(16))) float f32x16;

// ws layout (big path):
//   cnt    NR ints            per-key edge counts (memset 0)
//   slots  NR*16 ints         first <=16 src ids per key (no init needed)
//   WtH    9*16384 ushorts    W^T bf16 hi    WtL same (lo)
//   Mh     NR*D ushorts       bf16-hi means (102.4 MB)
//   xb     N*D ushorts        bf16 x table (12.8 MB)
#define FIXED_WS_BYTES ((size_t)NR * (1 + SLOTS_K) * 4 + (size_t)2 * 9 * 16384 * 2)
#define BIG_WS_BYTES (FIXED_WS_BYTES + (size_t)NR * D * 2 + (size_t)N_NODES * D * 2)

static __device__ __forceinline__ ushort_t f2bf(float f) {
    uint_t u = __float_as_uint(f);
    uint_t r = u + 0x7fffu + ((u >> 16) & 1u);
    return (ushort_t)(r >> 16);
}
static __device__ __forceinline__ float bf2f(ushort_t h) {
    return __uint_as_float(((uint_t)h) << 16);
}

// Direct global->LDS DMA, 16B per lane. LDS dest = wave-uniform base + lane*16.
static __device__ __forceinline__ void gload_lds16(const void* g, void* l) {
    __builtin_amdgcn_global_load_lds(
        (const __attribute__((address_space(1))) unsigned int*)g,
        (__attribute__((address_space(3))) unsigned int*)l, 16, 0, 0);
}

// x fp32 -> bf16 table (one-time; same rounding as gemm's old in-reg f2bf)
__global__ void __launch_bounds__(256)
xb_kernel(const float* __restrict__ x, ushort_t* __restrict__ xb) {
    int i = blockIdx.x * 256 + threadIdx.x;  // grid covers N*D/8 exactly
    const float4* xp = (const float4*)(x + (size_t)i * 8);
    float4 f0 = xp[0], f1 = xp[1];
    ushort8 h;
    h[0] = f2bf(f0.x); h[1] = f2bf(f0.y); h[2] = f2bf(f0.z); h[3] = f2bf(f0.w);
    h[4] = f2bf(f1.x); h[5] = f2bf(f1.y); h[6] = f2bf(f1.z); h[7] = f2bf(f1.w);
    *(ushort8*)(xb + (size_t)i * 8) = h;
}

// BIG path: count + first-16 slot table
__global__ void __launch_bounds__(256)
count_slots_kernel(const int* __restrict__ ei, const int* __restrict__ et,
                   int* __restrict__ cnt, int* __restrict__ slots) {
    int e = blockIdx.x * 256 + threadIdx.x;
    if (e < E_EDGES) {
        int src = ei[e];
        int dst = ei[E_EDGES + e];
        int r = et[e];
        int key = r * N_NODES + dst;
        int pos = atomicAdd(&cnt[key], 1);
        if (pos < SLOTS_K) slots[(size_t)key * SLOTS_K + pos] = src;
    }
}

// One-time: W[r][k][col] fp32 -> Wt[r][col][k] bf16 hi/lo. 36 blocks = (r, k0/32).
__global__ void __launch_bounds__(256)
wt_kernel(const float* __restrict__ W, const float* __restrict__ Wroot,
          ushort_t* __restrict__ WtH, ushort_t* __restrict__ WtL) {
    int r = blockIdx.x >> 2;
    int k0 = (blockIdx.x & 3) * 32;
    const float* Wr = (r < 8) ? (W + ((size_t)r << 14)) : Wroot;
    __shared__ float T[32][129];
    int tid = threadIdx.x;
#pragma unroll
    for (int u = 0; u < 16; ++u) {
        int idx = tid + u * 256;
        T[idx >> 7][idx & 127] = Wr[(size_t)k0 * D + idx];
    }
    __syncthreads();
    int col = tid & 127, kh = tid >> 7;
    ushort8 h0, h1, l0, l1;
#pragma unroll
    for (int kk = 0; kk < 8; ++kk) {
        float f = T[kh * 16 + kk][col];
        ushort_t hb = f2bf(f);
        h0[kk] = hb; l0[kk] = f2bf(f - bf2f(hb));
    }
#pragma unroll
    for (int kk = 0; kk < 8; ++kk) {
        float f = T[kh * 16 + 8 + kk][col];
        ushort_t hb = f2bf(f);
        h1[kk] = hb; l1[kk] = f2bf(f - bf2f(hb));
    }
    size_t o = ((size_t)r << 14) + (size_t)col * D + k0 + kh * 16;
    *(ushort8*)&WtH[o] = h0; *(ushort8*)&WtH[o + 8] = h1;
    *(ushort8*)&WtL[o] = l0; *(ushort8*)&WtL[o + 8] = l1;
}

// BIG kernel 1: one 16-lane group per key; bf16 gather; fp32 accumulate.
__global__ void __launch_bounds__(256)
mean_kernel(const ushort_t* __restrict__ xb, const int* __restrict__ ei,
            const int* __restrict__ et, const int* __restrict__ cnt,
            const int* __restrict__ slots, ushort_t* __restrict__ Mh) {
    int tid = threadIdx.x;
    int lane = tid & 63;
    int g = blockIdx.x * 16 + (tid >> 4);  // grid covers NR exactly
    int l = tid & 15;
    int gwb = lane & 48;                   // group base lane within wave
    int c = cnt[g];
    if (c == 0) return;

    float a[8] = {0.f, 0.f, 0.f, 0.f, 0.f, 0.f, 0.f, 0.f};
    if (c <= SLOTS_K) {
        int bw = 0;
        if (l < c) bw = slots[(size_t)g * SLOTS_K + l];  // lane-parallel prefetch
        for (int p0 = 0; p0 < c; p0 += 4) {
            int act = c - p0;
            ushort8 v[4];
#pragma unroll
            for (int u = 0; u < 4; ++u) {
                int src = __shfl(bw, gwb + p0 + u, 64);
                const ushort8* xp = (const ushort8*)(xb + (size_t)src * D + l * 8);
                if (u < act) v[u] = *xp;
            }
#pragma unroll
            for (int u = 0; u < 4; ++u) {
                if (u < act) {
#pragma unroll
                    for (int j = 0; j < 8; ++j) a[j] += bf2f(v[u][j]);
                }
            }
        }
    } else {
        // slow path: recompute the full sum from the edge list (deterministic)
        int rel = g / N_NODES;
        int dn = g - rel * N_NODES;
        for (int e = 0; e < E_EDGES; ++e) {
            if (et[e] == rel && ei[E_EDGES + e] == dn) {
                int src = ei[e];
                const ushort8* xp = (const ushort8*)(xb + (size_t)src * D + l * 8);
                ushort8 v = *xp;
#pragma unroll
                for (int j = 0; j < 8; ++j) a[j] += bf2f(v[j]);
            }
        }
    }
    float inv = 1.0f / (float)c;
    ushort8 h;
#pragma unroll
    for (int j = 0; j < 8; ++j) h[j] = f2bf(a[j] * inv);
    *(ushort8*)(Mh + (size_t)g * D + l * 8) = h;
}

// BIG kernel 2: dense GEMM, 2-phase pipelined, NOW 32x32x16 MFMA (half the
// LDS reads + half the MFMA instrs per FLOP vs 16x16x32). 8 waves = 4 row
// groups x 2 col groups; per wave 32 rows x 64 cols (2 tiles x f32x16 acc).
// A: row = lane&31, k = (lane>>5)*8+j (16B from Mh/xb). B: col = lane&31,
// same k (16B from swizzled LDS; slot distribution uniform -> b128 floor).
// C/D: col=lane&31, row=(reg&3)+8*(reg>>2)+4*(lane>>5) [m74/m101].
__global__ void __launch_bounds__(512, 4)
gemm_kernel(const ushort_t* __restrict__ xb, const ushort_t* __restrict__ Mh,
            const ushort_t* __restrict__ WtH, const ushort_t* __restrict__ WtL,
            const int* __restrict__ cnt, const float* __restrict__ bias,
            float* __restrict__ out) {
    __shared__ __align__(16) char Bc[65536];  // 2 bufs x (16KB Bh + 16KB Bl)
    int tid = threadIdx.x;
    int lane = tid & 63;
    int wave = tid >> 6;            // 0..7
    int rg = wave & 3;              // row group: rows rg*32..+31
    int cg = wave >> 2;             // col group: cols cg*64..+63
    int lrow = lane & 31;
    int lk = lane >> 5;             // k-half selector (0/1)
    int n0 = blockIdx.x * 128;
    int row = n0 + rg * 32 + lrow;
    int rowc = row < N_NODES ? row : N_NODES - 1;  // OOB masked in epilogue

    f32x16 acc0 = {0.f}, acc1 = {0.f};
#pragma unroll
    for (int j = 0; j < 16; ++j) { acc0[j] = 0.f; acc1[j] = 0.f; }

    auto stage = [&](int s, int bufIdx) {
        int rel = s >> 1, kh = s & 1;
        const char* pH = (const char*)(WtH + ((size_t)rel << 14));
        const char* pL = (const char*)(WtL + ((size_t)rel << 14));
        char* lb = Bc + bufIdx * 32768;
#pragma unroll
        for (int j = 0; j < 4; ++j) {
            int o = j * 8192 + wave * 1024 + lane * 16;  // linear within 32KB
            int oin = o & 16383;                         // within 16KB plane
            int osw = oin ^ ((oin >> 4) & 0x70);         // involution bits 4-6
            int gbyte = (osw >> 7) * 256 + kh * 128 + (osw & 127);
            const char* src = (o < 16384) ? (pH + gbyte) : (pL + gbyte);
            gload_lds16(src, lb + j * 8192 + wave * 1024);
        }
    };
    // A-fragments for stage s: 4 ksteps of K=16; 16B each at k = kh*64+ks*16+lk*8
    auto loadA = [&](int s, short8 (&a)[4]) {
        int rel = s >> 1, kh = s & 1;
        if (rel < 8) {
            int cv = cnt[rel * N_NODES + rowc];
            if (cv > 0) {
                const ushort_t* Ar = Mh + ((size_t)rel * N_NODES + rowc) * D;
#pragma unroll
                for (int ks = 0; ks < 4; ++ks)
                    a[ks] = *(const short8*)(Ar + kh * 64 + ks * 16 + lk * 8);
            } else {
#pragma unroll
                for (int ks = 0; ks < 4; ++ks)
#pragma unroll
                    for (int j = 0; j < 8; ++j) a[ks][j] = 0;
            }
        } else {
            const ushort_t* Ax = xb + (size_t)rowc * D;
#pragma unroll
            for (int ks = 0; ks < 4; ++ks)
                a[ks] = *(const short8*)(Ax + kh * 64 + ks * 16 + lk * 8);
        }
    };

    short8 aC[4], aN[4];
    stage(0, 0);
    loadA(0, aC);
    __syncthreads();  // drain stage 0

    for (int s = 0; s < 18; ++s) {
        int cur = s & 1;
        if (s < 17) { stage(s + 1, cur ^ 1); loadA(s + 1, aN); }
        const char* bb = Bc + cur * 32768;
#pragma unroll
        for (int ks = 0; ks < 4; ++ks) {
            // tile 0: cols cg*64 + lrow ; tile 1: +32 cols (rb + 4096)
            int rb0 = (cg * 64 + lrow) * 128 + ks * 32 + lk * 16;
            int rs0 = rb0 ^ ((rb0 >> 4) & 0x70);
            int rb1 = rb0 + 4096;
            int rs1 = rb1 ^ ((rb1 >> 4) & 0x70);
            short8 bh0 = *(const short8*)(bb + rs0);
            short8 bl0 = *(const short8*)(bb + 16384 + rs0);
            short8 bh1 = *(const short8*)(bb + rs1);
            short8 bl1 = *(const short8*)(bb + 16384 + rs1);
            acc0 = __builtin_amdgcn_mfma_f32_32x32x16_bf16(aC[ks], bh0, acc0, 0, 0, 0);
            acc0 = __builtin_amdgcn_mfma_f32_32x32x16_bf16(aC[ks], bl0, acc0, 0, 0, 0);
            acc1 = __builtin_amdgcn_mfma_f32_32x32x16_bf16(aC[ks], bh1, acc1, 0, 0, 0);
            acc1 = __builtin_amdgcn_mfma_f32_32x32x16_bf16(aC[ks], bl1, acc1, 0, 0, 0);
        }
        __syncthreads();  // drains stage s+1 loads; guards buffer reuse
        if (s < 17) {
#pragma unroll
            for (int ks = 0; ks < 4; ++ks) aC[ks] = aN[ks];
        }
    }

    // epilogue: 32x32 D layout col=lane&31, row=(reg&3)+8*(reg>>2)+4*lk
    {
        int col = cg * 64 + lrow;
        float bb = bias[col];
#pragma unroll
        for (int reg = 0; reg < 16; ++reg) {
            int nn = n0 + rg * 32 + (reg & 3) + 4 * lk + 8 * (reg >> 2);
            if (nn < N_NODES) {
                float v = acc0[reg] + bb;
                out[(size_t)nn * D + col] = v > 0.f ? v : 0.f;
            }
        }
    }
    {
        int col = cg * 64 + 32 + lrow;
        float bb = bias[col];
#pragma unroll
        for (int reg = 0; reg < 16; ++reg) {
            int nn = n0 + rg * 32 + (reg & 3) + 4 * lk + 8 * (reg >> 2);
            if (nn < N_NODES) {
                float v = acc1[reg] + bb;
                out[(size_t)nn * D + col] = v > 0.f ? v : 0.f;
            }
        }
    }
}

// ---------------- FALLBACK path (small ws; never taken per R8-14 evidence) --
__global__ void __launch_bounds__(256)
count_fb_kernel(const int* __restrict__ ei, const int* __restrict__ et,
                int* __restrict__ cnt) {
    int e = blockIdx.x * 256 + threadIdx.x;
    if (e < E_EDGES) {
        int dst = ei[E_EDGES + e];
        int r = et[e];
        atomicAdd(&cnt[r * N_NODES + dst], 1);
    }
}

__global__ void __launch_bounds__(256)
scan1_kernel(int* __restrict__ off, int* __restrict__ part) {
    __shared__ int wsum[4];
    int tid = threadIdx.x, lane = tid & 63, wid = tid >> 6;
    int base = blockIdx.x * 1024 + tid * 4;
    int c0 = 0, c1 = 0, c2 = 0, c3 = 0;
    if (base + 0 < NR) c0 = off[base + 0];
    if (base + 1 < NR) c1 = off[base + 1];
    if (base + 2 < NR) c2 = off[base + 2];
    if (base + 3 < NR) c3 = off[base + 3];
    int ts = c0 + c1 + c2 + c3;
    int v = ts;
#pragma unroll
    for (int o = 1; o < 64; o <<= 1) {
        int u = __shfl_up(v, o, 64);
        if (lane >= o) v += u;
    }
    if (lane == 63) wsum[wid] = v;
    __syncthreads();
    int wbase = 0;
#pragma unroll
    for (int w = 0; w < 4; ++w)
        if (w < wid) wbase += wsum[w];
    int excl = wbase + v - ts;
    if (base + 0 < NR) off[base + 0] = excl;
    if (base + 1 < NR) off[base + 1] = excl + c0;
    if (base + 2 < NR) off[base + 2] = excl + c0 + c1;
    if (base + 3 < NR) off[base + 3] = excl + c0 + c1 + c2;
    if (tid == 0) part[blockIdx.x] = wsum[0] + wsum[1] + wsum[2] + wsum[3];
}

__global__ void __launch_bounds__(512)
scan2_kernel(int* __restrict__ part) {
    __shared__ int ws8[8];
    int t = threadIdx.x, lane = t & 63, w = t >> 6;
    int v = (t < SCAN_BLOCKS) ? part[t] : 0;
    int s = v;
#pragma unroll
    for (int o = 1; o < 64; o <<= 1) {
        int u = __shfl_up(s, o, 64);
        if (lane >= o) s += u;
    }
    if (lane == 63) ws8[w] = s;
    __syncthreads();
    int wb = 0;
#pragma unroll
    for (int i = 0; i < 8; ++i)
        if (i < w) wb += ws8[i];
    if (t < SCAN_BLOCKS) part[t] = wb + s - v;
}

__global__ void __launch_bounds__(256)
scan3_kernel(int* __restrict__ off, const int* __restrict__ part) {
    int p = part[blockIdx.x];
    int base = blockIdx.x * 1024 + threadIdx.x * 4;
#pragma unroll
    for (int i = 0; i < 4; ++i)
        if (base + i < NR) off[base + i] += p;
}

__global__ void __launch_bounds__(256)
bucket_atomic_kernel(const int* __restrict__ ei, const int* __restrict__ et,
                     int* __restrict__ off, uint_t* __restrict__ bucket) {
    int e = blockIdx.x * 256 + threadIdx.x;
    if (e < E_EDGES) {
        int src = ei[e];
        int dst = ei[E_EDGES + e];
        int r = et[e];
        int key = r * N_NODES + dst;
        int pos = atomicAdd(&off[key], 1);
        bucket[pos] = (uint_t)src | ((uint_t)(dst & 63) << 17) | ((uint_t)r << 23);
    }
}

__global__ void __launch_bounds__(256, 4)
fused_kernel(const float* __restrict__ x,
             const ushort_t* __restrict__ WtH, const ushort_t* __restrict__ WtL,
             const float* __restrict__ bias, const int* __restrict__ ends,
             const uint_t* __restrict__ bucket, float* __restrict__ out) {
    __shared__ float At[64][132];
    __shared__ float sinv[64];
    __shared__ int sEnd[64];
    __shared__ float bs[128];
    __shared__ int sBase;

    int tid = threadIdx.x;
    int lane = tid & 63;
    int wave = tid >> 6;
    int mrow = lane & 15;
    int kg = lane >> 4;
    int n0 = blockIdx.x * 64;
    if (tid < 128) bs[tid] = bias[tid];

    f32x4 acc[8];
#pragma unroll
    for (int t = 0; t < 8; ++t) acc[t] = (f32x4){0.f, 0.f, 0.f, 0.f};

    for (int r = 0; r < R; ++r) {
        __syncthreads();
#pragma unroll
        for (int u = 0; u < 33; ++u) ((float*)At)[tid + u * 256] = 0.f;
        if (tid < 64) {
            int n = n0 + tid;
            if (n > N_NODES - 1) n = N_NODES - 1;
            int key = r * N_NODES + n;
            int e1 = ends[key];
            int e0 = (key == 0) ? 0 : ends[key - 1];
            int c = e1 - e0;
            sinv[tid] = (c > 0) ? 1.0f / (float)c : 0.0f;
            sEnd[tid] = e1;
            if (tid == 0) sBase = e0;
        }
        __syncthreads();
        int base = sBase;
        int nItems = (sEnd[63] - base) << 5;

        for (int i = tid; i < nItems; i += 256) {
            uint_t v = bucket[base + (i >> 5)];
            int src = v & 0x1FFFF;
            int dl = (v >> 17) & 63;
            int ch = i & 31;
            float4 xv = *(const float4*)(x + (size_t)src * D + ch * 4);
            float* rp = &At[dl][ch * 4];
            atomicAdd(rp + 0, xv.x);
            atomicAdd(rp + 1, xv.y);
            atomicAdd(rp + 2, xv.z);
            atomicAdd(rp + 3, xv.w);
        }
        __syncthreads();

        const ushort_t* WH = WtH + ((size_t)r << 14);
        const ushort_t* WL = WtL + ((size_t)r << 14);
        int rw = wave * 16 + mrow;
        float iv = sinv[rw];
#pragma unroll
        for (int kstep = 0; kstep < 4; ++kstep) {
            int kofs = kstep * 32 + kg * 8;
            float4 f0 = *(const float4*)&At[rw][kofs];
            float4 f1 = *(const float4*)&At[rw][kofs + 4];
            float fv[8] = {f0.x, f0.y, f0.z, f0.w, f1.x, f1.y, f1.z, f1.w};
            short8 ah, al;
#pragma unroll
            for (int j = 0; j < 8; ++j) {
                float f = fv[j] * iv;
                ushort_t hb = f2bf(f);
                ah[j] = (short)hb;
                al[j] = (short)f2bf(f - bf2f(hb));
            }
#pragma unroll
            for (int nt = 0; nt < 8; ++nt) {
                int col = nt * 16 + mrow;
                short8 bh = *(const short8*)&WH[(size_t)col * D + kofs];
                short8 bl = *(const short8*)&WL[(size_t)col * D + kofs];
                acc[nt] = __builtin_amdgcn_mfma_f32_16x16x32_bf16(ah, bh, acc[nt], 0, 0, 0);
                acc[nt] = __builtin_amdgcn_mfma_f32_16x16x32_bf16(ah, bl, acc[nt], 0, 0, 0);
                acc[nt] = __builtin_amdgcn_mfma_f32_16x16x32_bf16(al, bh, acc[nt], 0, 0, 0);
            }
        }
    }

    {
        const ushort_t* WH = WtH + ((size_t)8 << 14);
        const ushort_t* WL = WtL + ((size_t)8 << 14);
        int n = n0 + wave * 16 + mrow;
#pragma unroll
        for (int kstep = 0; kstep < 4; ++kstep) {
            int kofs = kstep * 32 + kg * 8;
            float fv[8] = {0.f, 0.f, 0.f, 0.f, 0.f, 0.f, 0.f, 0.f};
            if (n < N_NODES) {
                const float4* xp = (const float4*)(x + (size_t)n * D + kofs);
                float4 f0 = xp[0], f1 = xp[1];
                fv[0] = f0.x; fv[1] = f0.y; fv[2] = f0.z; fv[3] = f0.w;
                fv[4] = f1.x; fv[5] = f1.y; fv[6] = f1.z; fv[7] = f1.w;
            }
            short8 ah, al;
#pragma unroll
            for (int j = 0; j < 8; ++j) {
                float f = fv[j];
                ushort_t hb = f2bf(f);
                ah[j] = (short)hb;
                al[j] = (short)f2bf(f - bf2f(hb));
            }
#pragma unroll
            for (int nt = 0; nt < 8; ++nt) {
                int col = nt * 16 + mrow;
                short8 bh = *(const short8*)&WH[(size_t)col * D + kofs];
                short8 bl = *(const short8*)&WL[(size_t)col * D + kofs];
                acc[nt] = __builtin_amdgcn_mfma_f32_16x16x32_bf16(ah, bh, acc[nt], 0, 0, 0);
                acc[nt] = __builtin_amdgcn_mfma_f32_16x16x32_bf16(ah, bl, acc[nt], 0, 0, 0);
                acc[nt] = __builtin_amdgcn_mfma_f32_16x16x32_bf16(al, bh, acc[nt], 0, 0, 0);
            }
        }
    }

#pragma unroll
    for (int nt = 0; nt < 8; ++nt) {
        int col = nt * 16 + mrow;
        float bb = bs[col];
#pragma unroll
        for (int j = 0; j < 4; ++j) {
            int nn = n0 + wave * 16 + kg * 4 + j;
            if (nn < N_NODES) {
                float v = acc[nt][j] + bb;
                out[(size_t)nn * D + col] = v > 0.f ? v : 0.f;
            }
        }
    }
}

extern "C" void kernel_launch(void* const* d_in, const int* in_sizes, int n_in,
                              void* d_out, int out_size, void* d_ws, size_t ws_size,
                              hipStream_t stream) {
    const float* x     = (const float*)d_in[0];
    const int*   ei    = (const int*)d_in[1];
    const int*   et    = (const int*)d_in[2];
    const float* W     = (const float*)d_in[3];
    const float* Wroot = (const float*)d_in[4];
    const float* b     = (const float*)d_in[5];
    float* out = (float*)d_out;
    int* ws = (int*)d_ws;

    if (ws_size >= BIG_WS_BYTES) {
        int* cnt = ws;                                        // NR ints
        int* slots = ws + NR;                                 // NR*16 ints
        ushort_t* WtH = (ushort_t*)(ws + NR + NR * SLOTS_K);  // 9*16384 ushorts
        ushort_t* WtL = WtH + 9 * 16384;
        ushort_t* Mh = WtL + 9 * 16384;                       // NR*D bf16-hi
        ushort_t* xb = Mh + (size_t)NR * D;                   // N*D bf16

        hipMemsetAsync(cnt, 0, (size_t)NR * sizeof(int), stream);
        xb_kernel<<<(N_NODES * D) / (256 * 8), 256, 0, stream>>>(x, xb);
        count_slots_kernel<<<(E_EDGES + 255) / 256, 256, 0, stream>>>(ei, et, cnt,
                                                                      slots);
        wt_kernel<<<36, 256, 0, stream>>>(W, Wroot, WtH, WtL);
        mean_kernel<<<NR / 16, 256, 0, stream>>>(xb, ei, et, cnt, slots, Mh);
        gemm_kernel<<<(N_NODES + 127) / 128, 512, 0, stream>>>(xb, Mh, WtH, WtL, cnt,
                                                               b, out);
    } else {
        int* off = ws;                                   // NR ints
        uint_t* bucket = (uint_t*)(ws + NR);             // E packed words
        ushort_t* WtH = (ushort_t*)(ws + NR + E_EDGES);  // 9*16384 ushorts
        ushort_t* WtL = WtH + 9 * 16384;

        hipMemsetAsync(off, 0, (size_t)NR * sizeof(int), stream);
        count_fb_kernel<<<(E_EDGES + 255) / 256, 256, 0, stream>>>(ei, et, off);
        wt_kernel<<<36, 256, 0, stream>>>(W, Wroot, WtH, WtL);
        scan1_kernel<<<SCAN_BLOCKS, 256, 0, stream>>>(off, (int*)bucket);
        scan2_kernel<<<1, 512, 0, stream>>>((int*)bucket);
        scan3_kernel<<<SCAN_BLOCKS, 256, 0, stream>>>(off, (int*)bucket);
        bucket_atomic_kernel<<<(E_EDGES + 255) / 256, 256, 0, stream>>>(ei, et, off,
                                                                        bucket);
        fused_kernel<<<(N_NODES + 63) / 64, 256, 0, stream>>>(x, WtH, WtL, b, off,
                                                              bucket, out);
    }
}

// Round 16
// 122.967 us; speedup vs baseline: 1.0875x; 1.0875x over previous
//
#include <hip/hip_runtime.h>

#define N_NODES 50000
#define D 128
#define R 8
#define E_EDGES 600000
#define NR (N_NODES * R)                 // 400000 (rel,dst) keys: key = r*N + dst
#define SCAN_BLOCKS ((NR + 1023) / 1024) // 391 (fallback path only)
#define SLOTS_K 16

typedef unsigned short ushort_t;
typedef unsigned int uint_t;
typedef __attribute__((ext_vector_type(8))) short short8;
typedef __attribute__((ext_vector_type(8))) ushort_t ushort8;
typedef __attribute__((ext_vector_type(4))) float f32x4;

// ws layout (big path):
//   cnt    NR ints            per-key edge counts (memset 0); after mean_kernel,
//                             cnt==1 keys hold -(src+1) (gemm reads xb directly)
//   slots  NR*16 ints         first <=16 src ids per key (no init needed)
//   WtH    9*16384 ushorts    W^T bf16 hi    WtL same (lo)
//   Mh     NR*D ushorts       bf16-hi means (102.4 MB)
//   xb     N*D ushorts        bf16 x table (12.8 MB)
#define FIXED_WS_BYTES ((size_t)NR * (1 + SLOTS_K) * 4 + (size_t)2 * 9 * 16384 * 2)
#define BIG_WS_BYTES (FIXED_WS_BYTES + (size_t)NR * D * 2 + (size_t)N_NODES * D * 2)

static __device__ __forceinline__ ushort_t f2bf(float f) {
    uint_t u = __float_as_uint(f);
    uint_t r = u + 0x7fffu + ((u >> 16) & 1u);
    return (ushort_t)(r >> 16);
}
static __device__ __forceinline__ float bf2f(ushort_t h) {
    return __uint_as_float(((uint_t)h) << 16);
}

// Direct global->LDS DMA, 16B per lane. LDS dest = wave-uniform base + lane*16.
static __device__ __forceinline__ void gload_lds16(const void* g, void* l) {
    __builtin_amdgcn_global_load_lds(
        (const __attribute__((address_space(1))) unsigned int*)g,
        (__attribute__((address_space(3))) unsigned int*)l, 16, 0, 0);
}

// x fp32 -> bf16 table (one-time)
__global__ void __launch_bounds__(256)
xb_kernel(const float* __restrict__ x, ushort_t* __restrict__ xb) {
    int i = blockIdx.x * 256 + threadIdx.x;  // grid covers N*D/8 exactly
    const float4* xp = (const float4*)(x + (size_t)i * 8);
    float4 f0 = xp[0], f1 = xp[1];
    ushort8 h;
    h[0] = f2bf(f0.x); h[1] = f2bf(f0.y); h[2] = f2bf(f0.z); h[3] = f2bf(f0.w);
    h[4] = f2bf(f1.x); h[5] = f2bf(f1.y); h[6] = f2bf(f1.z); h[7] = f2bf(f1.w);
    *(ushort8*)(xb + (size_t)i * 8) = h;
}

// BIG path: count + first-16 slot table
__global__ void __launch_bounds__(256)
count_slots_kernel(const int* __restrict__ ei, const int* __restrict__ et,
                   int* __restrict__ cnt, int* __restrict__ slots) {
    int e = blockIdx.x * 256 + threadIdx.x;
    if (e < E_EDGES) {
        int src = ei[e];
        int dst = ei[E_EDGES + e];
        int r = et[e];
        int key = r * N_NODES + dst;
        int pos = atomicAdd(&cnt[key], 1);
        if (pos < SLOTS_K) slots[(size_t)key * SLOTS_K + pos] = src;
    }
}

// One-time: W[r][k][col] fp32 -> Wt[r][col][k] bf16 hi/lo. 36 blocks = (r, k0/32).
__global__ void __launch_bounds__(256)
wt_kernel(const float* __restrict__ W, const float* __restrict__ Wroot,
          ushort_t* __restrict__ WtH, ushort_t* __restrict__ WtL) {
    int r = blockIdx.x >> 2;
    int k0 = (blockIdx.x & 3) * 32;
    const float* Wr = (r < 8) ? (W + ((size_t)r << 14)) : Wroot;
    __shared__ float T[32][129];
    int tid = threadIdx.x;
#pragma unroll
    for (int u = 0; u < 16; ++u) {
        int idx = tid + u * 256;
        T[idx >> 7][idx & 127] = Wr[(size_t)k0 * D + idx];
    }
    __syncthreads();
    int col = tid & 127, kh = tid >> 7;
    ushort8 h0, h1, l0, l1;
#pragma unroll
    for (int kk = 0; kk < 8; ++kk) {
        float f = T[kh * 16 + kk][col];
        ushort_t hb = f2bf(f);
        h0[kk] = hb; l0[kk] = f2bf(f - bf2f(hb));
    }
#pragma unroll
    for (int kk = 0; kk < 8; ++kk) {
        float f = T[kh * 16 + 8 + kk][col];
        ushort_t hb = f2bf(f);
        h1[kk] = hb; l1[kk] = f2bf(f - bf2f(hb));
    }
    size_t o = ((size_t)r << 14) + (size_t)col * D + k0 + kh * 16;
    *(ushort8*)&WtH[o] = h0; *(ushort8*)&WtH[o + 8] = h1;
    *(ushort8*)&WtL[o] = l0; *(ushort8*)&WtL[o + 8] = l1;
}

// BIG kernel 1: one 16-lane group per key; bf16 gather; fp32 accumulate.
// cnt==0: skip. cnt==1 (43% of non-empty): skip gather AND Mh write entirely --
// mean==xb[src] bitwise (f2bf(bf2f(v)) identity), so encode cnt[g]=-(src+1)
// and let gemm read xb directly. cnt>16 (P~1e-5): deterministic full rescan.
__global__ void __launch_bounds__(256)
mean_kernel(const ushort_t* __restrict__ xb, const int* __restrict__ ei,
            const int* __restrict__ et, int* __restrict__ cnt,
            const int* __restrict__ slots, ushort_t* __restrict__ Mh) {
    int tid = threadIdx.x;
    int lane = tid & 63;
    int g = blockIdx.x * 16 + (tid >> 4);  // grid covers NR exactly
    int l = tid & 15;
    int gwb = lane & 48;                   // group base lane within wave
    int c = cnt[g];
    if (c == 0) return;
    if (c == 1) {
        if (l == 0) cnt[g] = -(slots[(size_t)g * SLOTS_K] + 1);
        return;
    }

    float a[8] = {0.f, 0.f, 0.f, 0.f, 0.f, 0.f, 0.f, 0.f};
    if (c <= SLOTS_K) {
        int bw = 0;
        if (l < c) bw = slots[(size_t)g * SLOTS_K + l];  // lane-parallel prefetch
        for (int p0 = 0; p0 < c; p0 += 4) {
            int act = c - p0;
            ushort8 v[4];
#pragma unroll
            for (int u = 0; u < 4; ++u) {
                int src = __shfl(bw, gwb + p0 + u, 64);
                const ushort8* xp = (const ushort8*)(xb + (size_t)src * D + l * 8);
                if (u < act) v[u] = *xp;
            }
#pragma unroll
            for (int u = 0; u < 4; ++u) {
                if (u < act) {
#pragma unroll
                    for (int j = 0; j < 8; ++j) a[j] += bf2f(v[u][j]);
                }
            }
        }
    } else {
        // slow path: recompute the full sum from the edge list (deterministic)
        int rel = g / N_NODES;
        int dn = g - rel * N_NODES;
        for (int e = 0; e < E_EDGES; ++e) {
            if (et[e] == rel && ei[E_EDGES + e] == dn) {
                int src = ei[e];
                const ushort8* xp = (const ushort8*)(xb + (size_t)src * D + l * 8);
                ushort8 v = *xp;
#pragma unroll
                for (int j = 0; j < 8; ++j) a[j] += bf2f(v[j]);
            }
        }
    }
    float inv = 1.0f / (float)c;
    ushort8 h;
#pragma unroll
    for (int j = 0; j < 8; ++j) h[j] = f2bf(a[j] * inv);
    *(ushort8*)(Mh + (size_t)g * D + l * 8) = h;
}

// BIG kernel 2: dense GEMM, 2-phase pipelined 16x16x32 (proven round 14; the
// 32x32 variant regressed -- 2 dependent acc chains vs 16 here). loadA:
// cv>0 -> Mh row; cv<0 -> xb[-cv-1] row (cnt==1 keys, L2/L3-hot); cv==0 -> 0.
__global__ void __launch_bounds__(512, 4)
gemm_kernel(const ushort_t* __restrict__ xb, const ushort_t* __restrict__ Mh,
            const ushort_t* __restrict__ WtH, const ushort_t* __restrict__ WtL,
            const int* __restrict__ cnt, const float* __restrict__ bias,
            float* __restrict__ out) {
    __shared__ __align__(16) char Bc[65536];  // 2 bufs x (16KB Bh + 16KB Bl)
    int tid = threadIdx.x;
    int lane = tid & 63;
    int wave = tid >> 6;            // 0..7
    int mrow = lane & 15;
    int kg = lane >> 4;
    int n0 = blockIdx.x * 128;
    int row = n0 + wave * 16 + mrow;
    int rowc = row < N_NODES ? row : N_NODES - 1;  // OOB masked in epilogue

    f32x4 acc[8];
#pragma unroll
    for (int t = 0; t < 8; ++t) acc[t] = (f32x4){0.f, 0.f, 0.f, 0.f};

    auto stage = [&](int s, int bufIdx) {
        int rel = s >> 1, kh = s & 1;
        const char* pH = (const char*)(WtH + ((size_t)rel << 14));
        const char* pL = (const char*)(WtL + ((size_t)rel << 14));
        char* lb = Bc + bufIdx * 32768;
#pragma unroll
        for (int j = 0; j < 4; ++j) {
            int o = j * 8192 + wave * 1024 + lane * 16;  // linear within 32KB
            int oin = o & 16383;                         // within 16KB plane
            int osw = oin ^ ((oin >> 4) & 0x70);         // involution bits 4-6
            int gbyte = (osw >> 7) * 256 + kh * 128 + (osw & 127);
            const char* src = (o < 16384) ? (pH + gbyte) : (pL + gbyte);
            gload_lds16(src, lb + j * 8192 + wave * 1024);
        }
    };
    auto loadA = [&](int s, short8* a) {
        int rel = s >> 1, kh = s & 1;
        if (rel < 8) {
            int cv = cnt[rel * N_NODES + rowc];
            if (cv > 0) {
                const ushort_t* Ar = Mh + ((size_t)rel * N_NODES + rowc) * D;
                a[0] = *(const short8*)(Ar + (kh * 2 + 0) * 32 + kg * 8);
                a[1] = *(const short8*)(Ar + (kh * 2 + 1) * 32 + kg * 8);
            } else if (cv < 0) {
                const ushort_t* Ar = xb + (size_t)(-cv - 1) * D;
                a[0] = *(const short8*)(Ar + (kh * 2 + 0) * 32 + kg * 8);
                a[1] = *(const short8*)(Ar + (kh * 2 + 1) * 32 + kg * 8);
            } else {
#pragma unroll
                for (int j = 0; j < 8; ++j) { a[0][j] = 0; a[1][j] = 0; }
            }
        } else {
            const ushort_t* Ax = xb + (size_t)rowc * D;
            a[0] = *(const short8*)(Ax + (kh * 2 + 0) * 32 + kg * 8);
            a[1] = *(const short8*)(Ax + (kh * 2 + 1) * 32 + kg * 8);
        }
    };

    short8 aC[2], aN[2];
    stage(0, 0);
    loadA(0, aC);
    __syncthreads();  // drain stage 0

    for (int s = 0; s < 18; ++s) {
        int cur = s & 1;
        if (s < 17) { stage(s + 1, cur ^ 1); loadA(s + 1, aN); }
        const char* bb = Bc + cur * 32768;
#pragma unroll
        for (int kl = 0; kl < 2; ++kl) {
#pragma unroll
            for (int nt = 0; nt < 8; ++nt) {
                int col = nt * 16 + mrow;
                int rb = col * 128 + kl * 64 + kg * 16;
                int rs = rb ^ ((rb >> 4) & 0x70);
                short8 bh = *(const short8*)(bb + rs);
                short8 bl = *(const short8*)(bb + 16384 + rs);
                acc[nt] = __builtin_amdgcn_mfma_f32_16x16x32_bf16(aC[kl], bh, acc[nt], 0, 0, 0);
                acc[nt] = __builtin_amdgcn_mfma_f32_16x16x32_bf16(aC[kl], bl, acc[nt], 0, 0, 0);
            }
        }
        __syncthreads();  // drains stage s+1 loads; guards buffer reuse
        if (s < 17) { aC[0] = aN[0]; aC[1] = aN[1]; }
    }

    // epilogue: D layout col=lane&15, row=(lane>>4)*4+j (verified rounds 5-14)
#pragma unroll
    for (int nt = 0; nt < 8; ++nt) {
        int col = nt * 16 + mrow;
        float bb = bias[col];
#pragma unroll
        for (int j = 0; j < 4; ++j) {
            int nn = n0 + wave * 16 + kg * 4 + j;
            if (nn < N_NODES) {
                float v = acc[nt][j] + bb;
                out[(size_t)nn * D + col] = v > 0.f ? v : 0.f;
            }
        }
    }
}

// ---------------- FALLBACK path (small ws; never taken per R8-15 evidence) --
__global__ void __launch_bounds__(256)
count_fb_kernel(const int* __restrict__ ei, const int* __restrict__ et,
                int* __restrict__ cnt) {
    int e = blockIdx.x * 256 + threadIdx.x;
    if (e < E_EDGES) {
        int dst = ei[E_EDGES + e];
        int r = et[e];
        atomicAdd(&cnt[r * N_NODES + dst], 1);
    }
}

__global__ void __launch_bounds__(256)
scan1_kernel(int* __restrict__ off, int* __restrict__ part) {
    __shared__ int wsum[4];
    int tid = threadIdx.x, lane = tid & 63, wid = tid >> 6;
    int base = blockIdx.x * 1024 + tid * 4;
    int c0 = 0, c1 = 0, c2 = 0, c3 = 0;
    if (base + 0 < NR) c0 = off[base + 0];
    if (base + 1 < NR) c1 = off[base + 1];
    if (base + 2 < NR) c2 = off[base + 2];
    if (base + 3 < NR) c3 = off[base + 3];
    int ts = c0 + c1 + c2 + c3;
    int v = ts;
#pragma unroll
    for (int o = 1; o < 64; o <<= 1) {
        int u = __shfl_up(v, o, 64);
        if (lane >= o) v += u;
    }
    if (lane == 63) wsum[wid] = v;
    __syncthreads();
    int wbase = 0;
#pragma unroll
    for (int w = 0; w < 4; ++w)
        if (w < wid) wbase += wsum[w];
    int excl = wbase + v - ts;
    if (base + 0 < NR) off[base + 0] = excl;
    if (base + 1 < NR) off[base + 1] = excl + c0;
    if (base + 2 < NR) off[base + 2] = excl + c0 + c1;
    if (base + 3 < NR) off[base + 3] = excl + c0 + c1 + c2;
    if (tid == 0) part[blockIdx.x] = wsum[0] + wsum[1] + wsum[2] + wsum[3];
}

__global__ void __launch_bounds__(512)
scan2_kernel(int* __restrict__ part) {
    __shared__ int ws8[8];
    int t = threadIdx.x, lane = t & 63, w = t >> 6;
    int v = (t < SCAN_BLOCKS) ? part[t] : 0;
    int s = v;
#pragma unroll
    for (int o = 1; o < 64; o <<= 1) {
        int u = __shfl_up(s, o, 64);
        if (lane >= o) s += u;
    }
    if (lane == 63) ws8[w] = s;
    __syncthreads();
    int wb = 0;
#pragma unroll
    for (int i = 0; i < 8; ++i)
        if (i < w) wb += ws8[i];
    if (t < SCAN_BLOCKS) part[t] = wb + s - v;
}

__global__ void __launch_bounds__(256)
scan3_kernel(int* __restrict__ off, const int* __restrict__ part) {
    int p = part[blockIdx.x];
    int base = blockIdx.x * 1024 + threadIdx.x * 4;
#pragma unroll
    for (int i = 0; i < 4; ++i)
        if (base + i < NR) off[base + i] += p;
}

__global__ void __launch_bounds__(256)
bucket_atomic_kernel(const int* __restrict__ ei, const int* __restrict__ et,
                     int* __restrict__ off, uint_t* __restrict__ bucket) {
    int e = blockIdx.x * 256 + threadIdx.x;
    if (e < E_EDGES) {
        int src = ei[e];
        int dst = ei[E_EDGES + e];
        int r = et[e];
        int key = r * N_NODES + dst;
        int pos = atomicAdd(&off[key], 1);
        bucket[pos] = (uint_t)src | ((uint_t)(dst & 63) << 17) | ((uint_t)r << 23);
    }
}

__global__ void __launch_bounds__(256, 4)
fused_kernel(const float* __restrict__ x,
             const ushort_t* __restrict__ WtH, const ushort_t* __restrict__ WtL,
             const float* __restrict__ bias, const int* __restrict__ ends,
             const uint_t* __restrict__ bucket, float* __restrict__ out) {
    __shared__ float At[64][132];
    __shared__ float sinv[64];
    __shared__ int sEnd[64];
    __shared__ float bs[128];
    __shared__ int sBase;

    int tid = threadIdx.x;
    int lane = tid & 63;
    int wave = tid >> 6;
    int mrow = lane & 15;
    int kg = lane >> 4;
    int n0 = blockIdx.x * 64;
    if (tid < 128) bs[tid] = bias[tid];

    f32x4 acc[8];
#pragma unroll
    for (int t = 0; t < 8; ++t) acc[t] = (f32x4){0.f, 0.f, 0.f, 0.f};

    for (int r = 0; r < R; ++r) {
        __syncthreads();
#pragma unroll
        for (int u = 0; u < 33; ++u) ((float*)At)[tid + u * 256] = 0.f;
        if (tid < 64) {
            int n = n0 + tid;
            if (n > N_NODES - 1) n = N_NODES - 1;
            int key = r * N_NODES + n;
            int e1 = ends[key];
            int e0 = (key == 0) ? 0 : ends[key - 1];
            int c = e1 - e0;
            sinv[tid] = (c > 0) ? 1.0f / (float)c : 0.0f;
            sEnd[tid] = e1;
            if (tid == 0) sBase = e0;
        }
        __syncthreads();
        int base = sBase;
        int nItems = (sEnd[63] - base) << 5;

        for (int i = tid; i < nItems; i += 256) {
            uint_t v = bucket[base + (i >> 5)];
            int src = v & 0x1FFFF;
            int dl = (v >> 17) & 63;
            int ch = i & 31;
            float4 xv = *(const float4*)(x + (size_t)src * D + ch * 4);
            float* rp = &At[dl][ch * 4];
            atomicAdd(rp + 0, xv.x);
            atomicAdd(rp + 1, xv.y);
            atomicAdd(rp + 2, xv.z);
            atomicAdd(rp + 3, xv.w);
        }
        __syncthreads();

        const ushort_t* WH = WtH + ((size_t)r << 14);
        const ushort_t* WL = WtL + ((size_t)r << 14);
        int rw = wave * 16 + mrow;
        float iv = sinv[rw];
#pragma unroll
        for (int kstep = 0; kstep < 4; ++kstep) {
            int kofs = kstep * 32 + kg * 8;
            float4 f0 = *(const float4*)&At[rw][kofs];
            float4 f1 = *(const float4*)&At[rw][kofs + 4];
            float fv[8] = {f0.x, f0.y, f0.z, f0.w, f1.x, f1.y, f1.z, f1.w};
            short8 ah, al;
#pragma unroll
            for (int j = 0; j < 8; ++j) {
                float f = fv[j] * iv;
                ushort_t hb = f2bf(f);
                ah[j] = (short)hb;
                al[j] = (short)f2bf(f - bf2f(hb));
            }
#pragma unroll
            for (int nt = 0; nt < 8; ++nt) {
                int col = nt * 16 + mrow;
                short8 bh = *(const short8*)&WH[(size_t)col * D + kofs];
                short8 bl = *(const short8*)&WL[(size_t)col * D + kofs];
                acc[nt] = __builtin_amdgcn_mfma_f32_16x16x32_bf16(ah, bh, acc[nt], 0, 0, 0);
                acc[nt] = __builtin_amdgcn_mfma_f32_16x16x32_bf16(ah, bl, acc[nt], 0, 0, 0);
                acc[nt] = __builtin_amdgcn_mfma_f32_16x16x32_bf16(al, bh, acc[nt], 0, 0, 0);
            }
        }
    }

    {
        const ushort_t* WH = WtH + ((size_t)8 << 14);
        const ushort_t* WL = WtL + ((size_t)8 << 14);
        int n = n0 + wave * 16 + mrow;
#pragma unroll
        for (int kstep = 0; kstep < 4; ++kstep) {
            int kofs = kstep * 32 + kg * 8;
            float fv[8] = {0.f, 0.f, 0.f, 0.f, 0.f, 0.f, 0.f, 0.f};
            if (n < N_NODES) {
                const float4* xp = (const float4*)(x + (size_t)n * D + kofs);
                float4 f0 = xp[0], f1 = xp[1];
                fv[0] = f0.x; fv[1] = f0.y; fv[2] = f0.z; fv[3] = f0.w;
                fv[4] = f1.x; fv[5] = f1.y; fv[6] = f1.z; fv[7] = f1.w;
            }
            short8 ah, al;
#pragma unroll
            for (int j = 0; j < 8; ++j) {
                float f = fv[j];
                ushort_t hb = f2bf(f);
                ah[j] = (short)hb;
                al[j] = (short)f2bf(f - bf2f(hb));
            }
#pragma unroll
            for (int nt = 0; nt < 8; ++nt) {
                int col = nt * 16 + mrow;
                short8 bh = *(const short8*)&WH[(size_t)col * D + kofs];
                short8 bl = *(const short8*)&WL[(size_t)col * D + kofs];
                acc[nt] = __builtin_amdgcn_mfma_f32_16x16x32_bf16(ah, bh, acc[nt], 0, 0, 0);
                acc[nt] = __builtin_amdgcn_mfma_f32_16x16x32_bf16(ah, bl, acc[nt], 0, 0, 0);
                acc[nt] = __builtin_amdgcn_mfma_f32_16x16x32_bf16(al, bh, acc[nt], 0, 0, 0);
            }
        }
    }

#pragma unroll
    for (int nt = 0; nt < 8; ++nt) {
        int col = nt * 16 + mrow;
        float bb = bs[col];
#pragma unroll
        for (int j = 0; j < 4; ++j) {
            int nn = n0 + wave * 16 + kg * 4 + j;
            if (nn < N_NODES) {
                float v = acc[nt][j] + bb;
                out[(size_t)nn * D + col] = v > 0.f ? v : 0.f;
            }
        }
    }
}

extern "C" void kernel_launch(void* const* d_in, const int* in_sizes, int n_in,
                              void* d_out, int out_size, void* d_ws, size_t ws_size,
                              hipStream_t stream) {
    const float* x     = (const float*)d_in[0];
    const int*   ei    = (const int*)d_in[1];
    const int*   et    = (const int*)d_in[2];
    const float* W     = (const float*)d_in[3];
    const float* Wroot = (const float*)d_in[4];
    const float* b     = (const float*)d_in[5];
    float* out = (float*)d_out;
    int* ws = (int*)d_ws;

    if (ws_size >= BIG_WS_BYTES) {
        int* cnt = ws;                                        // NR ints
        int* slots = ws + NR;                                 // NR*16 ints
        ushort_t* WtH = (ushort_t*)(ws + NR + NR * SLOTS_K);  // 9*16384 ushorts
        ushort_t* WtL = WtH + 9 * 16384;
        ushort_t* Mh = WtL + 9 * 16384;                       // NR*D bf16-hi
        ushort_t* xb = Mh + (size_t)NR * D;                   // N*D bf16

        hipMemsetAsync(cnt, 0, (size_t)NR * sizeof(int), stream);
        xb_kernel<<<(N_NODES * D) / (256 * 8), 256, 0, stream>>>(x, xb);
        count_slots_kernel<<<(E_EDGES + 255) / 256, 256, 0, stream>>>(ei, et, cnt,
                                                                      slots);
        wt_kernel<<<36, 256, 0, stream>>>(W, Wroot, WtH, WtL);
        mean_kernel<<<NR / 16, 256, 0, stream>>>(xb, ei, et, cnt, slots, Mh);
        gemm_kernel<<<(N_NODES + 127) / 128, 512, 0, stream>>>(xb, Mh, WtH, WtL, cnt,
                                                               b, out);
    } else {
        int* off = ws;                                   // NR ints
        uint_t* bucket = (uint_t*)(ws + NR);             // E packed words
        ushort_t* WtH = (ushort_t*)(ws + NR + E_EDGES);  // 9*16384 ushorts
        ushort_t* WtL = WtH + 9 * 16384;

        hipMemsetAsync(off, 0, (size_t)NR * sizeof(int), stream);
        count_fb_kernel<<<(E_EDGES + 255) / 256, 256, 0, stream>>>(ei, et, off);
        wt_kernel<<<36, 256, 0, stream>>>(W, Wroot, WtH, WtL);
        scan1_kernel<<<SCAN_BLOCKS, 256, 0, stream>>>(off, (int*)bucket);
        scan2_kernel<<<1, 512, 0, stream>>>((int*)bucket);
        scan3_kernel<<<SCAN_BLOCKS, 256, 0, stream>>>(off, (int*)bucket);
        bucket_atomic_kernel<<<(E_EDGES + 255) / 256, 256, 0, stream>>>(ei, et, off,
                                                                        bucket);
        fused_kernel<<<(N_NODES + 63) / 64, 256, 0, stream>>>(x, WtH, WtL, b, off,
                                                              bucket, out);
    }
}